// Round 9
// baseline (537.944 us; speedup 1.0000x reference)
//
#include <hip/hip_runtime.h>
#include <hip/hip_bf16.h>

#define B_ 128
#define T_ 512
#define H_ 128
#define V_ 64
#define G4_ 512  // 4*H

typedef _Float16 f16x8 __attribute__((ext_vector_type(8)));
typedef float f32x4 __attribute__((ext_vector_type(4)));
typedef _Float16 h2_t __attribute__((ext_vector_type(2)));
typedef _Float16 h8_t __attribute__((ext_vector_type(8)));
struct h8s { h2_t p[4]; };

__device__ __forceinline__ float dot2f(h2_t a, h2_t b, float c) {
#if __has_builtin(__builtin_amdgcn_fdot2)
  return __builtin_amdgcn_fdot2(a, b, c, false);
#else
  return fmaf((float)a[1], (float)b[1], fmaf((float)a[0], (float)b[0], c));
#endif
}

__device__ __forceinline__ float ex2(float x) {
#if __has_builtin(__builtin_amdgcn_exp2f)
  return __builtin_amdgcn_exp2f(x);
#else
  return exp2f(x);
#endif
}

__device__ __forceinline__ float rcpf_(float x) {
#if __has_builtin(__builtin_amdgcn_rcpf)
  return __builtin_amdgcn_rcpf(x);
#else
  return 1.0f / x;
#endif
}

__device__ __forceinline__ float sigm(float x) {
  return rcpf_(1.f + ex2(-1.4426950408889634f * x));
}
__device__ __forceinline__ float th(float x) {
  return fmaf(2.f, rcpf_(1.f + ex2(-2.8853900817779268f * x)), -1.f);
}

// ---------------------------------------------------------------------------
// K1: P2[dir][v][w][cc][g] = dot(emb[v,:], w_ih[dir][g*128+k,:]) + biases
// where k = w*16+cc. Gate index g is innermost so one lane's 4 gates for one
// batch load as a single dwordx4 in k_scan.
// ---------------------------------------------------------------------------
__global__ __launch_bounds__(512) void k_tables(
    const float* __restrict__ emb,
    const float* __restrict__ w_ih_f, const float* __restrict__ b_ih_f,
    const float* __restrict__ b_hh_f,
    const float* __restrict__ w_ih_b, const float* __restrict__ b_ih_b,
    const float* __restrict__ b_hh_b,
    float* __restrict__ Ptab) {
  const int dir = blockIdx.x >> 6;
  const int v = blockIdx.x & 63;
  const int j0 = threadIdx.x;  // row = g*128 + k
  const float* w_ih = dir ? w_ih_b : w_ih_f;
  const float* bi = dir ? b_ih_b : b_ih_f;
  const float* bh = dir ? b_hh_b : b_hh_f;
  const float4* e4 = (const float4*)(emb + v * H_);
  const float4* w4 = (const float4*)(w_ih + j0 * H_);
  float a0 = 0.f, a1 = 0.f, a2 = 0.f, a3 = 0.f;
#pragma unroll
  for (int q = 0; q < H_ / 4; ++q) {
    float4 e = e4[q];
    float4 w = w4[q];
    a0 = fmaf(e.x, w.x, a0);
    a1 = fmaf(e.y, w.y, a1);
    a2 = fmaf(e.z, w.z, a2);
    a3 = fmaf(e.w, w.w, a3);
  }
  const int g = j0 >> 7, k = j0 & 127;
  Ptab[dir * (V_ * G4_) + v * G4_ + ((k >> 4) << 6) + ((k & 15) << 2) + g] =
      (a0 + a1) + (a2 + a3) + bi[j0] + bh[j0];
}

// ---------------------------------------------------------------------------
// K2: MFMA scan. grid = 16 (dir = bid&1, batch-group bg = bid>>1, 16 seqs).
// 8 waves; wave w owns gate-cols {g*128 + w*16 + cc}. Lane (cc = l&15,
// grp = l>>4). Per step:
//   gates[16b][512] = mfma16x16x32_f16(A = h, B = w_hh cols, C = P prefetch)
//   D layout (m89): m = grp*4+reg = batch, n = cc -> k-col w*16+cc.
//   All 4 gates of (batch, k) land in-lane -> c/h update with zero exchange.
// h ring: hist[2][8][b][k] fp16, XOR-swizzled (byte ^= (b&7)<<4), written as
// 4x b16/lane, read back as A-frags via 4x ds_read_b128 (slot i <-> k base+i
// for BOTH A and B, so any internal MFMA slot ordering cancels).
// Flush 8 steps at a time to hs[t][b][256].
// ---------------------------------------------------------------------------
__global__ __launch_bounds__(512, 2) void k_scan(
    const int* __restrict__ x,
    const float* __restrict__ w_hh_f,
    const float* __restrict__ w_hh_b,
    const float* __restrict__ Ptab,
    _Float16* __restrict__ hs) {
  __shared__ __align__(16) _Float16 hist[2][8][16 * H_];  // 64 KB
  __shared__ int xoff[T_ * 16];                           // 32 KB, v<<11

  const int tid = threadIdx.x;
  const int w = tid >> 6, l = tid & 63, cc = l & 15, grp = l >> 4;
  const int dir = blockIdx.x & 1, bg = blockIdx.x >> 1;

  // stage x as byte offsets into P: xoff[t*16+bb] = x[b][t] * 2048
#pragma unroll
  for (int bb = 0; bb < 16; ++bb)
    xoff[tid * 16 + bb] = x[((bg * 16 + bb) << 9) + tid] << 11;

  // B-frags: B[k-slot][n=cc] = w_hh[tau*128 + w*16 + cc][kt*32 + grp*8 + i]
  const float* W = dir ? w_hh_b : w_hh_f;
  f16x8 Bf[4][4];
#pragma unroll
  for (int tau = 0; tau < 4; ++tau)
#pragma unroll
    for (int kt = 0; kt < 4; ++kt) {
      const int j = tau * H_ + w * 16 + cc;
      const int kb = kt * 32 + grp * 8;
      float4 u0 = *(const float4*)(W + j * H_ + kb);
      float4 u1 = *(const float4*)(W + j * H_ + kb + 4);
      Bf[tau][kt] = f16x8{(_Float16)u0.x, (_Float16)u0.y, (_Float16)u0.z,
                          (_Float16)u0.w, (_Float16)u1.x, (_Float16)u1.y,
                          (_Float16)u1.z, (_Float16)u1.w};
    }

  // zero the "step -1" h slot: hist[1][7] (4 KB)
  {
    unsigned* hz = (unsigned*)&hist[1][7][0];
    hz[tid] = 0;
    hz[tid + 512] = 0;
  }

  float c0 = 0.f, c1 = 0.f, c2 = 0.f, c3 = 0.f;
  __syncthreads();

  // A-frag read offsets: (b=cc, k = kt*32+grp*8..+8), swizzled
  const int swa = (cc & 7) << 4;
  int aoff[4];
#pragma unroll
  for (int kt = 0; kt < 4; ++kt)
    aoff[kt] = cc * 256 + ((kt * 64 + grp * 16) ^ swa);

  // h write offsets: (b = grp*4+r, k = w*16+cc), swizzled
  int woff[4];
#pragma unroll
  for (int r = 0; r < 4; ++r) {
    const int b = grp * 4 + r;
    woff[r] = b * 256 + ((w * 32 + cc * 2) ^ ((b & 7) << 4));
  }

  const char* Pb =
      (const char*)(Ptab + (size_t)dir * (V_ * G4_) + w * 64 + cc * 4);

  // prefetch step-0 P: per batch r one float4 {i,f,g,o}; transpose to per-gate
  f32x4 pA, pB, pC, pD;
  {
    const int t0 = dir ? (T_ - 1) : 0;
    int4 xv = *(const int4*)&xoff[t0 * 16 + grp * 4];
    float4 q0 = *(const float4*)(Pb + xv.x);
    float4 q1 = *(const float4*)(Pb + xv.y);
    float4 q2 = *(const float4*)(Pb + xv.z);
    float4 q3 = *(const float4*)(Pb + xv.w);
    pA = f32x4{q0.x, q1.x, q2.x, q3.x};
    pB = f32x4{q0.y, q1.y, q2.y, q3.y};
    pC = f32x4{q0.z, q1.z, q2.z, q3.z};
    pD = f32x4{q0.w, q1.w, q2.w, q3.w};
  }

  for (int s = 0; s < T_; ++s) {
    // A-frags from h of step s-1 (slot (s-1)&15; s=0 -> zeroed hist[1][7])
    const int pm = (s + 15) & 15;
    const char* hsrc = (const char*)&hist[pm >> 3][pm & 7][0];
    f16x8 A0 = *(const f16x8*)(hsrc + aoff[0]);
    f16x8 A1 = *(const f16x8*)(hsrc + aoff[1]);
    f16x8 A2 = *(const f16x8*)(hsrc + aoff[2]);
    f16x8 A3 = *(const f16x8*)(hsrc + aoff[3]);

    // prefetch next step's P
    const int sn = (s < T_ - 1) ? s + 1 : s;
    const int tn = dir ? (T_ - 1 - sn) : sn;
    int4 xv = *(const int4*)&xoff[tn * 16 + grp * 4];
    float4 q0 = *(const float4*)(Pb + xv.x);
    float4 q1 = *(const float4*)(Pb + xv.y);
    float4 q2 = *(const float4*)(Pb + xv.z);
    float4 q3 = *(const float4*)(Pb + xv.w);

    // MFMA: acc_tau starts from P (input proj + biases); 4 K-tiles
    f32x4 a0 = pA, a1 = pB, a2 = pC, a3 = pD;
    a0 = __builtin_amdgcn_mfma_f32_16x16x32_f16(A0, Bf[0][0], a0, 0, 0, 0);
    a1 = __builtin_amdgcn_mfma_f32_16x16x32_f16(A0, Bf[1][0], a1, 0, 0, 0);
    a2 = __builtin_amdgcn_mfma_f32_16x16x32_f16(A0, Bf[2][0], a2, 0, 0, 0);
    a3 = __builtin_amdgcn_mfma_f32_16x16x32_f16(A0, Bf[3][0], a3, 0, 0, 0);
    a0 = __builtin_amdgcn_mfma_f32_16x16x32_f16(A1, Bf[0][1], a0, 0, 0, 0);
    a1 = __builtin_amdgcn_mfma_f32_16x16x32_f16(A1, Bf[1][1], a1, 0, 0, 0);
    a2 = __builtin_amdgcn_mfma_f32_16x16x32_f16(A1, Bf[2][1], a2, 0, 0, 0);
    a3 = __builtin_amdgcn_mfma_f32_16x16x32_f16(A1, Bf[3][1], a3, 0, 0, 0);
    a0 = __builtin_amdgcn_mfma_f32_16x16x32_f16(A2, Bf[0][2], a0, 0, 0, 0);
    a1 = __builtin_amdgcn_mfma_f32_16x16x32_f16(A2, Bf[1][2], a1, 0, 0, 0);
    a2 = __builtin_amdgcn_mfma_f32_16x16x32_f16(A2, Bf[2][2], a2, 0, 0, 0);
    a3 = __builtin_amdgcn_mfma_f32_16x16x32_f16(A2, Bf[3][2], a3, 0, 0, 0);
    a0 = __builtin_amdgcn_mfma_f32_16x16x32_f16(A3, Bf[0][3], a0, 0, 0, 0);
    a1 = __builtin_amdgcn_mfma_f32_16x16x32_f16(A3, Bf[1][3], a1, 0, 0, 0);
    a2 = __builtin_amdgcn_mfma_f32_16x16x32_f16(A3, Bf[2][3], a2, 0, 0, 0);
    a3 = __builtin_amdgcn_mfma_f32_16x16x32_f16(A3, Bf[3][3], a3, 0, 0, 0);

    // tail: a0=i, a1=f, a2=g~, a3=o ; reg r = batch grp*4+r
    float hv0, hv1, hv2, hv3;
    {
      float yi = sigm(a0[0]), yf = sigm(a1[0]), yg = th(a2[0]), yo = sigm(a3[0]);
      c0 = fmaf(yf, c0, yi * yg);
      hv0 = yo * th(c0);
    }
    {
      float yi = sigm(a0[1]), yf = sigm(a1[1]), yg = th(a2[1]), yo = sigm(a3[1]);
      c1 = fmaf(yf, c1, yi * yg);
      hv1 = yo * th(c1);
    }
    {
      float yi = sigm(a0[2]), yf = sigm(a1[2]), yg = th(a2[2]), yo = sigm(a3[2]);
      c2 = fmaf(yf, c2, yi * yg);
      hv2 = yo * th(c2);
    }
    {
      float yi = sigm(a0[3]), yf = sigm(a1[3]), yg = th(a2[3]), yo = sigm(a3[3]);
      c3 = fmaf(yf, c3, yi * yg);
      hv3 = yo * th(c3);
    }

    // write h of step s into ring slot s&15
    const int pc = s & 15;
    char* hdst = (char*)&hist[pc >> 3][pc & 7][0];
    *(_Float16*)(hdst + woff[0]) = (_Float16)hv0;
    *(_Float16*)(hdst + woff[1]) = (_Float16)hv1;
    *(_Float16*)(hdst + woff[2]) = (_Float16)hv2;
    *(_Float16*)(hdst + woff[3]) = (_Float16)hv3;

    pA = f32x4{q0.x, q1.x, q2.x, q3.x};
    pB = f32x4{q0.y, q1.y, q2.y, q3.y};
    pC = f32x4{q0.z, q1.z, q2.z, q3.z};
    pD = f32x4{q0.w, q1.w, q2.w, q3.w};

    __syncthreads();

    if ((s & 7) == 7) {
      // flush 8 completed steps: hist[ph][tl][b][k] -> hs[t][b][k]
      const int ph = (s >> 3) & 1;
      const int sb = s - 7;
#pragma unroll
      for (int i = 0; i < 4; ++i) {
        const int chunk = tid + i * 512;
        const int kc = chunk & 15, b = (chunk >> 4) & 15, tl = (chunk >> 8) & 7;
        const int tb = dir ? (T_ - 1 - (sb + tl)) : (sb + tl);
        f16x8 vv = *(const f16x8*)((const char*)&hist[ph][tl][0] + b * 256 +
                                   ((kc * 16) ^ ((b & 7) << 4)));
        *(f16x8*)((unsigned short*)hs +
                  (((size_t)tb * B_ + bg * 16 + b) << 8) + (dir << 7) +
                  (kc << 3)) = vv;
      }
    }
  }
}

// ---------------------------------------------------------------------------
// K3: out[b][t][v] = dot(hs[t][b][0:256], fc_w[v,:]) + fc_b[v]
// hs row (t*128+b) = blockIdx*256+tid, contiguous 256 fp16.
// ---------------------------------------------------------------------------
__global__ __launch_bounds__(256) void k_fc(
    const _Float16* __restrict__ hs,
    const float* __restrict__ fc_w,
    const float* __restrict__ fc_b,
    float* __restrict__ out) {
  __shared__ __align__(16) _Float16 Wl[V_ * 2 * H_];  // 32 KB
  __shared__ float bl[V_];
  const int tid = threadIdx.x;
  for (int i = tid; i < V_ * 2 * H_; i += 256) Wl[i] = (_Float16)fc_w[i];
  if (tid < V_) bl[tid] = fc_b[tid];
  __syncthreads();

  const size_t row = (size_t)blockIdx.x * 256 + tid;
  const h8_t* h8 = (const h8_t*)(hs + (row << 8));
  float acc[V_];
#pragma unroll
  for (int v = 0; v < V_; ++v) acc[v] = 0.f;

  for (int ch = 0; ch < 8; ++ch) {
    h8s hv0 = __builtin_bit_cast(h8s, h8[ch * 4 + 0]);
    h8s hv1 = __builtin_bit_cast(h8s, h8[ch * 4 + 1]);
    h8s hv2 = __builtin_bit_cast(h8s, h8[ch * 4 + 2]);
    h8s hv3 = __builtin_bit_cast(h8s, h8[ch * 4 + 3]);
#pragma unroll
    for (int v = 0; v < V_; ++v) {
      const h8_t* w8 = (const h8_t*)(Wl + v * 256 + ch * 32);
      float a = acc[v];
      h8s wv = __builtin_bit_cast(h8s, w8[0]);
      a = dot2f(hv0.p[0], wv.p[0], a);
      a = dot2f(hv0.p[1], wv.p[1], a);
      a = dot2f(hv0.p[2], wv.p[2], a);
      a = dot2f(hv0.p[3], wv.p[3], a);
      wv = __builtin_bit_cast(h8s, w8[1]);
      a = dot2f(hv1.p[0], wv.p[0], a);
      a = dot2f(hv1.p[1], wv.p[1], a);
      a = dot2f(hv1.p[2], wv.p[2], a);
      a = dot2f(hv1.p[3], wv.p[3], a);
      wv = __builtin_bit_cast(h8s, w8[2]);
      a = dot2f(hv2.p[0], wv.p[0], a);
      a = dot2f(hv2.p[1], wv.p[1], a);
      a = dot2f(hv2.p[2], wv.p[2], a);
      a = dot2f(hv2.p[3], wv.p[3], a);
      wv = __builtin_bit_cast(h8s, w8[3]);
      a = dot2f(hv3.p[0], wv.p[0], a);
      a = dot2f(hv3.p[1], wv.p[1], a);
      a = dot2f(hv3.p[2], wv.p[2], a);
      a = dot2f(hv3.p[3], wv.p[3], a);
      acc[v] = a;
    }
  }
  const int t = (int)(row >> 7), gb = (int)(row & 127);
  float* orow = out + (((size_t)gb << 9) + t) * V_;
#pragma unroll
  for (int v = 0; v < V_; v += 4) {
    float4 o = make_float4(acc[v] + bl[v], acc[v + 1] + bl[v + 1],
                           acc[v + 2] + bl[v + 2], acc[v + 3] + bl[v + 3]);
    *(float4*)(orow + v) = o;
  }
}

extern "C" void kernel_launch(void* const* d_in, const int* in_sizes, int n_in,
                              void* d_out, int out_size, void* d_ws, size_t ws_size,
                              hipStream_t stream) {
  const int* x = (const int*)d_in[0];
  const float* emb = (const float*)d_in[1];
  const float* w_ih_f = (const float*)d_in[2];
  const float* w_hh_f = (const float*)d_in[3];
  const float* b_ih_f = (const float*)d_in[4];
  const float* b_hh_f = (const float*)d_in[5];
  const float* w_ih_b = (const float*)d_in[6];
  const float* w_hh_b = (const float*)d_in[7];
  const float* b_ih_b = (const float*)d_in[8];
  const float* b_hh_b = (const float*)d_in[9];
  const float* fc_w = (const float*)d_in[10];
  const float* fc_b = (const float*)d_in[11];
  float* out = (float*)d_out;

  // workspace: [P2 tables 256 KB][hs: T*B*256 fp16 = 32 MB, layout [t][b][256]]
  float* Ptab = (float*)d_ws;
  _Float16* hs = (_Float16*)((char*)d_ws + (size_t)2 * V_ * G4_ * sizeof(float));

  k_tables<<<2 * V_, G4_, 0, stream>>>(emb, w_ih_f, b_ih_f, b_hh_f, w_ih_b,
                                       b_ih_b, b_hh_b, Ptab);
  k_scan<<<16, 512, 0, stream>>>(x, w_hh_f, w_hh_b, Ptab, hs);
  k_fc<<<B_ * T_ / 256, 256, 0, stream>>>(hs, fc_w, fc_b, out);
}